// Round 15
// baseline (83.471 us; speedup 1.0000x reference)
//
#include <hip/hip_runtime.h>
#include <cstdint>
#include <cstddef>

typedef __attribute__((ext_vector_type(8))) short short8;
typedef __attribute__((ext_vector_type(4))) short short4v;
typedef __attribute__((ext_vector_type(4))) float f32x4;
typedef short8 bf16x8;

typedef __attribute__((address_space(1))) const unsigned GU;
typedef __attribute__((address_space(3))) unsigned LU;

__device__ __forceinline__ short f2bf(float f) {
  unsigned u = __builtin_bit_cast(unsigned, f);
  u += 0x7fffu + ((u >> 16) & 1u);   // RNE; inputs are finite normals
  return (short)(u >> 16);
}

// ---------------- fused: cast x (f32->bf16) + weight transpose ----------------
__global__ __launch_bounds__(256) void k_prep(const float* __restrict__ x,
                                              const float* __restrict__ W0, const float* __restrict__ W1,
                                              const float* __restrict__ W2, const float* __restrict__ W3,
                                              short* __restrict__ xb, short* __restrict__ WT) {
  __shared__ short T[64 * 72];
  int bid = blockIdx.x;
  int tid = threadIdx.x;
  if (bid < 2048) {
    size_t i = ((size_t)bid * 256 + tid) * 8;
    f32x4 a = *(const f32x4*)(x + i);
    f32x4 b = *(const f32x4*)(x + i + 4);
    short8 o;
#pragma unroll
    for (int j = 0; j < 4; ++j) { o[j] = f2bf(a[j]); o[4 + j] = f2bf(b[j]); }
    *(short8*)(xb + i) = o;
    return;
  }
  bid -= 2048;
  int widx = bid >> 8;
  int t = bid & 255;
  int kr = (t >> 4) * 64, nc = (t & 15) * 64;
  const float* W = widx == 0 ? W0 : widx == 1 ? W1 : widx == 2 ? W2 : W3;
  short* out = WT + (size_t)widx * 1048576;
#pragma unroll
  for (int i = 0; i < 4; ++i) {
    int idx = tid + i * 256;          // 1024 quads of 4 floats
    int k = idx >> 4, n4 = (idx & 15) << 2;
    f32x4 v = *(const f32x4*)(W + (size_t)(kr + k) * 1024 + nc + n4);
#pragma unroll
    for (int j = 0; j < 4; ++j) T[(n4 + j) * 72 + k] = f2bf(v[j]);
  }
  __syncthreads();
#pragma unroll
  for (int i = 0; i < 2; ++i) {
    int idx = tid + i * 256;
    int n = idx >> 3, k8 = (idx & 7) << 3;
    *(short8*)(out + (size_t)(nc + n) * 1024 + kr + k8) = *(const short8*)&T[n * 72 + k8];
  }
}

// ================= 128M x 192N QKV GEMM — 4-phase counted waits @ 2 blocks/CU ==========
// C[4096,3072] = A[4096,1024] * BT[3072,1024]^T, bf16 in, fp32 acc, bf16 out (+bias).
// grid 512 = 32tm x 16tn (2 blocks/CU). 512 thr = 8 waves; wave = 64 rows (wm) x 48 cols
// (wn): acc[4][3]. LDS exactly 80KB: A 2buf x 2reg @ {0,8192}+r*4096; B 2buf x 3reg @
// 16384 + buf*12288 + r*4096 (shorts). 2 blocks/CU covers residual stage latency (m114).
// Per K-tile T (bufs t&1), 4 phases {reads; stages; BAR; lgkm(0); 6 MFMA; BAR}:
//  P0: read kk0 (aA x4, aB x3); stage A(T+1).r0, B(T+1).r0
//  P1: read kk1 (cA x4, cB x3); stage A(T+1).r1, B(T+1).r1
//  P2: stage B(T+1).r2
//  P3: vmcnt(0) (drains T+1 stages; ~1-phase exposure, sibling block covers)
// Liveness: nA/nB (T+1 targets) last read at T-1.P0/P1, retired >=2 barriers before
// T.P0's stage. Last iter stages tile 15 again (dead rewrites, drained in epilogue).
__global__ __launch_bounds__(512, 4) void k_gemm256(
    const short* __restrict__ A, const short* __restrict__ BT,
    const float* __restrict__ bias0, const float* __restrict__ bias1, const float* __restrict__ bias2,
    short* __restrict__ outb) {
  __shared__ short S[40960];
  const int tid = threadIdx.x;
  const int lane = tid & 63, w = tid >> 6;
  const int g = lane >> 4, qi = lane & 15;
  const int wm = w >> 2, wn = w & 3;
  int bid = blockIdx.x;
  int xcd = bid & 7, ii = bid >> 3;           // 64 tiles per XCD, 8tm x 8tn rectangle
  const int tm = (xcd >> 1) * 8 + (ii >> 3);
  const int tn = (xcd & 1) * 8 + (ii & 7);
  const int m0 = tm * 128, n0 = tn * 192;
  const size_t K = 1024;
  const short* Ab = A + (size_t)m0 * K;
  const short* Bb = BT + (size_t)n0 * K;

  auto stage64 = [&](int roff, const short* gbase, int kt) {
    int r = tid >> 3;
    int js = ((tid & 7) ^ (r & 7)) << 3;      // pre-swizzled global chunk
    __builtin_amdgcn_global_load_lds((GU*)(gbase + (size_t)r * K + kt * 64 + js),
                                     (LU*)(&S[roff + tid * 8]), 16, 0, 0);
  };
  auto lda_a = [&](int abase, int mf, int kk) -> bf16x8 {
    int row = mf * 16 + qi;                   // region = wm
    return *(const bf16x8*)&S[abase + wm * 4096 + row * 64 + (((kk * 4 + g) ^ (row & 7)) << 3)];
  };
  auto lda_b = [&](int bbase, int nf, int kk) -> bf16x8 {
    int c = wn * 48 + nf * 16 + qi;
    int reg = c >> 6, row = c & 63;
    return *(const bf16x8*)&S[bbase + reg * 4096 + row * 64 + (((kk * 4 + g) ^ (row & 7)) << 3)];
  };

  f32x4 acc[4][3];
#pragma unroll
  for (int i = 0; i < 4; ++i)
#pragma unroll
    for (int j = 0; j < 3; ++j) acc[i][j] = (f32x4)(0.0f);

#define MFA(mi, ni, av, bv) \
  acc[mi][ni] = __builtin_amdgcn_mfma_f32_16x16x32_bf16(av, bv, acc[mi][ni], 0, 0, 0)
#define MF6(Aa, Bb_, o) \
  MFA((o)+0,0,(Aa)[(o)+0],(Bb_)[0]); MFA((o)+0,1,(Aa)[(o)+0],(Bb_)[1]); MFA((o)+0,2,(Aa)[(o)+0],(Bb_)[2]); \
  MFA((o)+1,0,(Aa)[(o)+1],(Bb_)[0]); MFA((o)+1,1,(Aa)[(o)+1],(Bb_)[1]); MFA((o)+1,2,(Aa)[(o)+1],(Bb_)[2])
#define SB __builtin_amdgcn_sched_barrier(0)
#define PHASE_TAIL(MFMAS) do { \
    SB; \
    __builtin_amdgcn_s_barrier(); \
    asm volatile("s_waitcnt lgkmcnt(0)" ::: "memory"); \
    SB; \
    __builtin_amdgcn_s_setprio(1); \
    MFMAS; \
    __builtin_amdgcn_s_setprio(0); \
    SB; \
    __builtin_amdgcn_s_barrier(); \
  } while (0)

  // prologue: tile 0 (A r0,r1 + B r0,r1,r2) into buf0
  stage64(0,             Ab,          0);
  stage64(4096,          Ab + 65536,  0);
  stage64(16384,         Bb,          0);
  stage64(16384 + 4096,  Bb + 65536,  0);
  stage64(16384 + 8192,  Bb + 131072, 0);
  asm volatile("s_waitcnt vmcnt(0)" ::: "memory");
  __builtin_amdgcn_s_barrier();

  for (int t = 0; t < 16; ++t) {
    const int rA = (t & 1) * 8192, nA = rA ^ 8192;
    const int rB = 16384 + (t & 1) * 12288;
    const int nB = 16384 + ((t + 1) & 1) * 12288;
    const int t1 = t + 1 < 15 ? t + 1 : 15;
    bf16x8 aA[4], aB[3], cA[4], cB[3];

    // ---- P0: reads kk0; stage A(T+1).r0, B(T+1).r0 ----
#pragma unroll
    for (int mf = 0; mf < 4; ++mf) aA[mf] = lda_a(rA, mf, 0);
#pragma unroll
    for (int nf = 0; nf < 3; ++nf) aB[nf] = lda_b(rB, nf, 0);
    stage64(nA, Ab, t1);
    stage64(nB, Bb, t1);
    PHASE_TAIL(MF6(aA, aB, 0));
    // ---- P1: reads kk1; stage A(T+1).r1, B(T+1).r1 ----
#pragma unroll
    for (int mf = 0; mf < 4; ++mf) cA[mf] = lda_a(rA, mf, 1);
#pragma unroll
    for (int nf = 0; nf < 3; ++nf) cB[nf] = lda_b(rB, nf, 1);
    stage64(nA + 4096, Ab + 65536, t1);
    stage64(nB + 4096, Bb + 65536, t1);
    PHASE_TAIL(MF6(aA, aB, 2));
    // ---- P2: stage B(T+1).r2 ----
    stage64(nB + 8192, Bb + 131072, t1);
    PHASE_TAIL(MF6(cA, cB, 0));
    // ---- P3: drain T+1 stages ----
    asm volatile("s_waitcnt vmcnt(0)" ::: "memory");
    PHASE_TAIL(MF6(cA, cB, 2));
  }
#undef PHASE_TAIL
#undef MF6
#undef MFA
#undef SB

  // epilogue: drain dead last-iter stages, LDS-transpose, coalesced bf16 stores
  asm volatile("s_waitcnt vmcnt(0)" ::: "memory");
  __syncthreads();
  float bv[3];
#pragma unroll
  for (int nf = 0; nf < 3; ++nf) {
    int colg = n0 + wn * 48 + nf * 16 + qi;
    int sel = colg >> 10;
    const float* bias = sel == 0 ? bias0 : (sel == 1 ? bias1 : bias2);
    bv[nf] = bias[colg & 1023];
  }
  short* Ep = S;                                       // [128][200] = 25600 shorts
#pragma unroll
  for (int mf = 0; mf < 4; ++mf)
#pragma unroll
    for (int nf = 0; nf < 3; ++nf)
#pragma unroll
      for (int j = 0; j < 4; ++j)
        Ep[(wm * 64 + mf * 16 + g * 4 + j) * 200 + wn * 48 + nf * 16 + qi] =
            f2bf(acc[mf][nf][j] + bv[nf]);
  __syncthreads();
#pragma unroll
  for (int i = 0; i < 6; ++i) {
    int idx = tid + i * 512;                           // 3072 chunks of 8 bf16
    int r = idx / 24, c8 = (idx % 24) * 8;
    int grow = m0 + r;
    int colg = n0 + c8;
    int sel = colg >> 10;
    *(short8*)&outb[(size_t)sel * 4194304 + (size_t)grow * 1024 + (colg & 1023)] =
        *(const short8*)&Ep[r * 200 + c8];
  }
}

// ---------------- final GEMM (128^2): out = attn_out * WoT^T + bo ----------------
// 1D grid 256 with 2D XCD map: each XCD owns an 8tm x 4tn rectangle (3MB L2 footprint).
__global__ __launch_bounds__(256, 2) void k_gemmO(
    const short* __restrict__ A, const short* __restrict__ BT,
    const float* __restrict__ bias0, float* __restrict__ outf) {
  __shared__ short Smem[16384];
  const int tid = threadIdx.x;
  const int lane = tid & 63, w = tid >> 6;
  const int g = lane >> 4, qi = lane & 15;
  const int wr = (w >> 1) * 64, wc = (w & 1) * 64;
  int bid = blockIdx.x;
  int xcd = bid & 7, ii = bid >> 3;            // 32 tiles per XCD: 8tm x 4tn
  const int tm = (xcd >> 1) * 8 + (ii >> 2);
  const int tn = (xcd & 1) * 4 + (ii & 3);
  const int m0 = tm * 128, n0 = tn * 128;
  const size_t K = 1024;
  const short* Ab = A + (size_t)m0 * K;
  const short* Bb = BT + (size_t)n0 * K;

  auto stage = [&](int buf, int k0) {
    short* Asb = Smem + buf * 4096;
    short* Bsb = Smem + 8192 + buf * 4096;
#pragma unroll
    for (int i = 0; i < 2; ++i) {
      int cidx = tid + i * 256;
      int r = cidx >> 2;
      int csw = ((cidx & 3) ^ ((r >> 1) & 3)) << 3;
      __builtin_amdgcn_global_load_lds((GU*)(Ab + (size_t)r * K + k0 + csw),
                                       (LU*)(&Asb[cidx * 8]), 16, 0, 0);
      __builtin_amdgcn_global_load_lds((GU*)(Bb + (size_t)r * K + k0 + csw),
                                       (LU*)(&Bsb[cidx * 8]), 16, 0, 0);
    }
  };

  f32x4 acc[4][4];
#pragma unroll
  for (int i = 0; i < 4; ++i)
#pragma unroll
    for (int j = 0; j < 4; ++j) acc[i][j] = (f32x4)(0.0f);

  stage(0, 0);
  __syncthreads();
  for (int kt = 0; kt < 32; ++kt) {
    int cur = kt & 1;
    if (kt < 31) stage(cur ^ 1, (kt + 1) * 32);
    const short* Asb = Smem + cur * 4096;
    const short* Bsb = Smem + 8192 + cur * 4096;
    bf16x8 a[4], b[4];
#pragma unroll
    for (int mf = 0; mf < 4; ++mf) {
      int R = wr + mf * 16 + qi;
      a[mf] = *(const bf16x8*)&Asb[R * 32 + ((g ^ ((R >> 1) & 3)) << 3)];
    }
#pragma unroll
    for (int nf = 0; nf < 4; ++nf) {
      int R = wc + nf * 16 + qi;
      b[nf] = *(const bf16x8*)&Bsb[R * 32 + ((g ^ ((R >> 1) & 3)) << 3)];
    }
#pragma unroll
    for (int mf = 0; mf < 4; ++mf)
#pragma unroll
      for (int nf = 0; nf < 4; ++nf)
        acc[mf][nf] = __builtin_amdgcn_mfma_f32_16x16x32_bf16(a[mf], b[nf], acc[mf][nf], 0, 0, 0);
    __syncthreads();
  }

  float* Ft = (float*)Smem;                  // [32][136]
  float bv[4];
#pragma unroll
  for (int nf = 0; nf < 4; ++nf) bv[nf] = bias0[n0 + wc + nf * 16 + qi];
#pragma unroll
  for (int mf = 0; mf < 4; ++mf) {
    __syncthreads();
#pragma unroll
    for (int nf = 0; nf < 4; ++nf)
#pragma unroll
      for (int j = 0; j < 4; ++j)
        Ft[((w >> 1) * 16 + g * 4 + j) * 136 + wc + nf * 16 + qi] = acc[mf][nf][j] + bv[nf];
    __syncthreads();
#pragma unroll
    for (int i = 0; i < 4; ++i) {
      int idx = tid + i * 256;
      int r = idx >> 5, c4 = (idx & 31) << 2;
      int row = m0 + ((r >> 4) << 6) + mf * 16 + (r & 15);
      *(f32x4*)&outf[(size_t)row * 1024 + n0 + c4] = *(const f32x4*)&Ft[r * 136 + c4];
    }
  }
}

// ---------------- banded flash attention (round-13: Q-hoist + interior mask skip) ----------------
__global__ __launch_bounds__(256, 2) void k_attn(const short* __restrict__ qg_,
                                                 const short* __restrict__ kg_,
                                                 const short* __restrict__ vg_,
                                                 short* __restrict__ outp) {
  __shared__ short Qs[64 * 72];
  __shared__ short Ks[64 * 72];
  __shared__ short Vs[64 * 72];
  __shared__ short Ps[4][16 * 72];
  int bid = blockIdx.x;
  int qt = bid & 31, h = (bid >> 5) & 15, b = bid >> 9;
  int q0 = qt * 64;
  int tid = threadIdx.x, lane = tid & 63, w = tid >> 6;
  int g = lane >> 4, qi = lane & 15;

  const short* qsrc = qg_ + ((size_t)b * 2048 + q0) * 1024 + h * 64;
#pragma unroll
  for (int i = 0; i < 2; ++i) {
    int idx = tid + i * 256;
    int r = idx >> 3, c = (idx & 7) << 3;
    *(short8*)&Qs[r * 72 + c] = *(const short8*)&qsrc[(size_t)r * 1024 + c];
  }
  __syncthreads();
  bf16x8 qf0 = *(const bf16x8*)&Qs[(w * 16 + qi) * 72 + g * 8];
  bf16x8 qf1 = *(const bf16x8*)&Qs[(w * 16 + qi) * 72 + 32 + g * 8];

  float m = -1e30f, l = 0.f;
  f32x4 oacc[4];
#pragma unroll
  for (int i = 0; i < 4; ++i) oacc[i] = (f32x4)(0.0f);
  int qglob = q0 + w * 16 + qi;

  for (int cc = 0; cc < 5; ++cc) {
    int kb0 = q0 - 128 + cc * 64;
    if (kb0 < 0 || kb0 >= 2048) continue;
    __syncthreads();
    const short* ksrc = kg_ + ((size_t)b * 2048 + kb0) * 1024 + h * 64;
    const short* vsrc = vg_ + ((size_t)b * 2048 + kb0) * 1024 + h * 64;
#pragma unroll
    for (int i = 0; i < 2; ++i) {
      int idx = tid + i * 256;
      int r = idx >> 3, c = (idx & 7) << 3;
      *(short8*)&Ks[r * 72 + c] = *(const short8*)&ksrc[(size_t)r * 1024 + c];
      short8 vv = *(const short8*)&vsrc[(size_t)r * 1024 + c];
#pragma unroll
      for (int j = 0; j < 8; ++j) {
        int d = c + j;
        Vs[d * 72 + ((r + ((d >> 3) << 3)) & 63)] = vv[j];
      }
    }
    __syncthreads();

    f32x4 st[4];
#pragma unroll
    for (int i = 0; i < 4; ++i) st[i] = (f32x4)(0.0f);
#pragma unroll
    for (int mf = 0; mf < 4; ++mf) {
      bf16x8 kf0 = *(const bf16x8*)&Ks[(mf * 16 + qi) * 72 + g * 8];
      bf16x8 kf1 = *(const bf16x8*)&Ks[(mf * 16 + qi) * 72 + 32 + g * 8];
      st[mf] = __builtin_amdgcn_mfma_f32_16x16x32_bf16(kf0, qf0, st[mf], 0, 0, 0);
      st[mf] = __builtin_amdgcn_mfma_f32_16x16x32_bf16(kf1, qf1, st[mf], 0, 0, 0);
    }

    float pv[16];
    float pm = -1e30f;
    if (cc >= 1 && cc <= 3) {           // interior chunks: always inside the band
#pragma unroll
      for (int mf = 0; mf < 4; ++mf)
#pragma unroll
        for (int j = 0; j < 4; ++j) {
          float s = st[mf][j] * 0.125f;
          pv[mf * 4 + j] = s;
          pm = fmaxf(pm, s);
        }
    } else {
#pragma unroll
      for (int mf = 0; mf < 4; ++mf)
#pragma unroll
        for (int j = 0; j < 4; ++j) {
          int kcol = kb0 + mf * 16 + g * 4 + j;
          float s = st[mf][j] * 0.125f;
          int d = kcol - qglob;
          bool valid = (d >= -128) && (d <= 128);
          s = valid ? s : -1e30f;
          pv[mf * 4 + j] = s;
          pm = fmaxf(pm, s);
        }
    }
    pm = fmaxf(pm, __shfl_xor(pm, 16));
    pm = fmaxf(pm, __shfl_xor(pm, 32));
    float mnew = fmaxf(m, pm);
    float scale = __expf(m - mnew);
    float ls = 0.f;
#pragma unroll
    for (int e = 0; e < 16; ++e) {
      float p = pv[e] > -1e29f ? __expf(pv[e] - mnew) : 0.f;
      pv[e] = p;
      ls += p;
    }
    ls += __shfl_xor(ls, 16);
    ls += __shfl_xor(ls, 32);
    l = l * scale + ls;
    m = mnew;
#pragma unroll
    for (int mf = 0; mf < 4; ++mf) oacc[mf] *= scale;

#pragma unroll
    for (int f = 0; f < 4; ++f) {
      short4v pk;
#pragma unroll
      for (int j = 0; j < 4; ++j) pk[j] = f2bf(pv[f * 4 + j]);
      *(short4v*)&Ps[w][qi * 72 + f * 16 + g * 4] = pk;
    }

#pragma unroll
    for (int ks = 0; ks < 2; ++ks) {
      bf16x8 pf = *(const bf16x8*)&Ps[w][qi * 72 + ks * 32 + g * 8];
#pragma unroll
      for (int mf = 0; mf < 4; ++mf) {
        int dd = mf * 16 + qi;
        int pc = ((ks * 32 + g * 8) + ((dd >> 3) << 3)) & 63;
        bf16x8 vf = *(const bf16x8*)&Vs[dd * 72 + pc];
        oacc[mf] = __builtin_amdgcn_mfma_f32_16x16x32_bf16(vf, pf, oacc[mf], 0, 0, 0);
      }
    }
  }

  __syncthreads();
  short* Os = Ks;
  float inv = 1.f / l;
#pragma unroll
  for (int mf = 0; mf < 4; ++mf) {
    short4v pk;
#pragma unroll
    for (int j = 0; j < 4; ++j) pk[j] = f2bf(oacc[mf][j] * inv);
    *(short4v*)&Os[(w * 16 + qi) * 72 + mf * 16 + g * 4] = pk;
  }
  __syncthreads();
  short* dst = outp + ((size_t)b * 2048 + q0) * 1024 + h * 64;
  int r = tid >> 2, c16 = (tid & 3) << 4;
  *(short8*)&dst[(size_t)r * 1024 + c16] = *(const short8*)&Os[r * 72 + c16];
  *(short8*)&dst[(size_t)r * 1024 + c16 + 8] = *(const short8*)&Os[r * 72 + c16 + 8];
}

extern "C" void kernel_launch(void* const* d_in, const int* in_sizes, int n_in,
                              void* d_out, int out_size, void* d_ws, size_t ws_size,
                              hipStream_t stream) {
  const float* x  = (const float*)d_in[0];
  const float* Wq = (const float*)d_in[1];
  const float* bq = (const float*)d_in[2];
  const float* Wk = (const float*)d_in[3];
  const float* bk = (const float*)d_in[4];
  const float* Wv = (const float*)d_in[5];
  const float* bv = (const float*)d_in[6];
  const float* Wo = (const float*)d_in[7];
  const float* bo = (const float*)d_in[8];

  short* ws = (short*)d_ws;
  // layout (shorts): [0,4M) xb (dead after QKV GEMM) -> attn_out ; [4M,16M) q,k,v ;
  // [16M,20M) WqT,WkT,WvT,WoT.  v stays live through k_attn (read directly).
  short* xb       = ws;
  short* qkv      = ws + 4194304;
  short* vbuf     = qkv + 2 * 4194304;
  short* attn_out = ws;            // aliases xb (dead after QKV GEMM)
  short* WT       = ws + 4 * 4194304;

  k_prep<<<3072, 256, 0, stream>>>(x, Wq, Wk, Wv, Wo, xb, WT);
  k_gemm256<<<512, 512, 0, stream>>>(xb, WT, bq, bk, bv, qkv);
  k_attn<<<1024, 256, 0, stream>>>(qkv, qkv + 4194304, vbuf, attn_out);
  k_gemmO<<<256, 256, 0, stream>>>(attn_out, WT + 3 * 1048576, bo, (float*)d_out);
}

// Round 16
// 82.063 us; speedup vs baseline: 1.0171x; 1.0171x over previous
//
#include <hip/hip_runtime.h>
#include <cstdint>
#include <cstddef>

typedef __attribute__((ext_vector_type(8))) short short8;
typedef __attribute__((ext_vector_type(4))) short short4v;
typedef __attribute__((ext_vector_type(4))) float f32x4;
typedef short8 bf16x8;

typedef __attribute__((address_space(1))) const unsigned GU;
typedef __attribute__((address_space(3))) unsigned LU;

__device__ __forceinline__ short f2bf(float f) {
  unsigned u = __builtin_bit_cast(unsigned, f);
  u += 0x7fffu + ((u >> 16) & 1u);   // RNE; inputs are finite normals
  return (short)(u >> 16);
}

// ---------------- fused: cast x (f32->bf16) + weight transpose ----------------
__global__ __launch_bounds__(256) void k_prep(const float* __restrict__ x,
                                              const float* __restrict__ W0, const float* __restrict__ W1,
                                              const float* __restrict__ W2, const float* __restrict__ W3,
                                              short* __restrict__ xb, short* __restrict__ WT) {
  __shared__ short T[64 * 72];
  int bid = blockIdx.x;
  int tid = threadIdx.x;
  if (bid < 2048) {
    size_t i = ((size_t)bid * 256 + tid) * 8;
    f32x4 a = *(const f32x4*)(x + i);
    f32x4 b = *(const f32x4*)(x + i + 4);
    short8 o;
#pragma unroll
    for (int j = 0; j < 4; ++j) { o[j] = f2bf(a[j]); o[4 + j] = f2bf(b[j]); }
    *(short8*)(xb + i) = o;
    return;
  }
  bid -= 2048;
  int widx = bid >> 8;
  int t = bid & 255;
  int kr = (t >> 4) * 64, nc = (t & 15) * 64;
  const float* W = widx == 0 ? W0 : widx == 1 ? W1 : widx == 2 ? W2 : W3;
  short* out = WT + (size_t)widx * 1048576;
#pragma unroll
  for (int i = 0; i < 4; ++i) {
    int idx = tid + i * 256;          // 1024 quads of 4 floats
    int k = idx >> 4, n4 = (idx & 15) << 2;
    f32x4 v = *(const f32x4*)(W + (size_t)(kr + k) * 1024 + nc + n4);
#pragma unroll
    for (int j = 0; j < 4; ++j) T[(n4 + j) * 72 + k] = f2bf(v[j]);
  }
  __syncthreads();
#pragma unroll
  for (int i = 0; i < 2; ++i) {
    int idx = tid + i * 256;
    int n = idx >> 3, k8 = (idx & 7) << 3;
    *(short8*)(out + (size_t)(nc + n) * 1024 + kr + k8) = *(const short8*)&T[n * 72 + k8];
  }
}

// ================= 256M x 192N QKV GEMM — round-13-best configuration ==========
__global__ __launch_bounds__(512, 1) void k_gemm256(
    const short* __restrict__ A, const short* __restrict__ BT,
    const float* __restrict__ bias0, const float* __restrict__ bias1, const float* __restrict__ bias2,
    short* __restrict__ outb) {
  __shared__ short S[57344];
  const int tid = threadIdx.x;
  const int lane = tid & 63, w = tid >> 6;
  const int g = lane >> 4, qi = lane & 15;
  const int wm = w >> 2, wn = w & 3;
  int bid = blockIdx.x;
  int xcd = bid & 7, ii = bid >> 3;           // 32 tiles per XCD, 4x8 rectangle
  const int tm = (xcd >> 1) * 4 + (ii >> 3);
  const int tn = (xcd & 1) * 8 + (ii & 7);
  const int m0 = tm * 256, n0 = tn * 192;
  const size_t K = 1024;
  const short* Ab = A + (size_t)m0 * K;
  const short* Bb = BT + (size_t)n0 * K;

  auto stage64 = [&](int roff, const short* gbase, int kt) {
    int r = tid >> 3;
    int js = ((tid & 7) ^ (r & 7)) << 3;      // pre-swizzled global chunk
    __builtin_amdgcn_global_load_lds((GU*)(gbase + (size_t)r * K + kt * 64 + js),
                                     (LU*)(&S[roff + tid * 8]), 16, 0, 0);
  };
  auto lda_a = [&](int bbase, int mf, int kk) -> bf16x8 {
    int row = (mf & 3) * 16 + qi;
    int reg = wm * 2 + (mf >> 2);
    return *(const bf16x8*)&S[bbase + reg * 4096 + row * 64 + (((kk * 4 + g) ^ (row & 7)) << 3)];
  };
  auto lda_b = [&](int bbase, int nf, int kk) -> bf16x8 {
    int c = wn * 48 + nf * 16 + qi;
    int reg = c >> 6, row = c & 63;
    return *(const bf16x8*)&S[bbase + 16384 + reg * 4096 + row * 64 + (((kk * 4 + g) ^ (row & 7)) << 3)];
  };

  f32x4 acc[8][3];
#pragma unroll
  for (int i = 0; i < 8; ++i)
#pragma unroll
    for (int j = 0; j < 3; ++j) acc[i][j] = (f32x4)(0.0f);

#define MFA(mi, ni, av, bv) \
  acc[mi][ni] = __builtin_amdgcn_mfma_f32_16x16x32_bf16(av, bv, acc[mi][ni], 0, 0, 0)
#define MF12(Aa, Bb_, o) \
  MFA((o)+0,0,(Aa)[(o)+0],(Bb_)[0]); MFA((o)+0,1,(Aa)[(o)+0],(Bb_)[1]); MFA((o)+0,2,(Aa)[(o)+0],(Bb_)[2]); \
  MFA((o)+1,0,(Aa)[(o)+1],(Bb_)[0]); MFA((o)+1,1,(Aa)[(o)+1],(Bb_)[1]); MFA((o)+1,2,(Aa)[(o)+1],(Bb_)[2]); \
  MFA((o)+2,0,(Aa)[(o)+2],(Bb_)[0]); MFA((o)+2,1,(Aa)[(o)+2],(Bb_)[1]); MFA((o)+2,2,(Aa)[(o)+2],(Bb_)[2]); \
  MFA((o)+3,0,(Aa)[(o)+3],(Bb_)[0]); MFA((o)+3,1,(Aa)[(o)+3],(Bb_)[1]); MFA((o)+3,2,(Aa)[(o)+3],(Bb_)[2])
#define SB __builtin_amdgcn_sched_barrier(0)
#define PHASE_TAIL(MFMAS) do { \
    SB; \
    __builtin_amdgcn_s_barrier(); \
    asm volatile("s_waitcnt lgkmcnt(0)" ::: "memory"); \
    SB; \
    __builtin_amdgcn_s_setprio(1); \
    MFMAS; \
    __builtin_amdgcn_s_setprio(0); \
    SB; \
    __builtin_amdgcn_s_barrier(); \
  } while (0)

  // prologue: T0 (A0-3,B0-2) into buf0 + T1.B0-2 into buf1
  stage64(0,     Ab,            0);
  stage64(4096,  Ab + 65536,    0);
  stage64(8192,  Ab + 131072,   0);
  stage64(12288, Ab + 196608,   0);
  stage64(16384, Bb,            0);
  stage64(20480, Bb + 65536,    0);
  stage64(24576, Bb + 131072,   0);
  stage64(28672 + 16384, Bb,          1);
  stage64(28672 + 20480, Bb + 65536,  1);
  stage64(28672 + 24576, Bb + 131072, 1);
  asm volatile("s_waitcnt vmcnt(3)" ::: "memory");   // T0 landed; T1.B in flight
  __builtin_amdgcn_s_barrier();

  for (int t = 0; t < 16; ++t) {
    const int b = t & 1, nb = b ^ 1;
    const int bb = b * 28672, nbb = nb * 28672;
    const int t1 = t + 1 < 15 ? t + 1 : 15;
    const int t2 = t + 2 < 15 ? t + 2 : 15;
    bf16x8 aA[8], aB[3], cA[8], cB[3];

    // ---- P0 ----
#pragma unroll
    for (int mf = 0; mf < 4; ++mf) aA[mf] = lda_a(bb, mf, 0);
#pragma unroll
    for (int nf = 0; nf < 3; ++nf) aB[nf] = lda_b(bb, nf, 0);
    stage64(nbb,        Ab,         t1);             // (T+1).A0
    stage64(nbb + 4096, Ab + 65536, t1);             // (T+1).A1
    PHASE_TAIL(MF12(aA, aB, 0));
    // ---- P1 ----
#pragma unroll
    for (int mf = 4; mf < 8; ++mf) aA[mf] = lda_a(bb, mf, 0);
#pragma unroll
    for (int nf = 0; nf < 3; ++nf) cB[nf] = lda_b(bb, nf, 1);
    stage64(nbb + 8192,  Ab + 131072, t1);           // (T+1).A2
    stage64(nbb + 12288, Ab + 196608, t1);           // (T+1).A3
    PHASE_TAIL(MF12(aA, aB, 4));
    // ---- P2 ----
#pragma unroll
    for (int mf = 0; mf < 4; ++mf) cA[mf] = lda_a(bb, mf, 1);
    stage64(bb + 16384, Bb,         t2);             // (T+2).B0
    stage64(bb + 20480, Bb + 65536, t2);             // (T+2).B1
    PHASE_TAIL(MF12(cA, cB, 0));
    // ---- P3 ----
#pragma unroll
    for (int mf = 4; mf < 8; ++mf) cA[mf] = lda_a(bb, mf, 1);
    stage64(bb + 24576, Bb + 131072, t2);            // (T+2).B2
    asm volatile("s_waitcnt vmcnt(3)" ::: "memory"); // (T+1) fully landed
    PHASE_TAIL(MF12(cA, cB, 4));
  }
#undef PHASE_TAIL
#undef MF12
#undef MFA
#undef SB

  // epilogue: drain clamped stages, then LDS-transpose coalesced bf16 stores
  asm volatile("s_waitcnt vmcnt(0)" ::: "memory");
  __syncthreads();
  float bv[3];
#pragma unroll
  for (int nf = 0; nf < 3; ++nf) {
    int colg = n0 + wn * 48 + nf * 16 + qi;
    int sel = colg >> 10;
    const float* bias = sel == 0 ? bias0 : (sel == 1 ? bias1 : bias2);
    bv[nf] = bias[colg & 1023];
  }
  short* Ep = S;                                       // [128][200]
#pragma unroll
  for (int p = 0; p < 2; ++p) {
    __syncthreads();
    if (wm == p) {
#pragma unroll
      for (int mf = 0; mf < 8; ++mf)
#pragma unroll
        for (int nf = 0; nf < 3; ++nf)
#pragma unroll
          for (int j = 0; j < 4; ++j)
            Ep[(mf * 16 + g * 4 + j) * 200 + wn * 48 + nf * 16 + qi] =
                f2bf(acc[mf][nf][j] + bv[nf]);
    }
    __syncthreads();
#pragma unroll
    for (int i = 0; i < 6; ++i) {
      int idx = tid + i * 512;                         // 3072 chunks of 8 bf16
      int r = idx / 24, c8 = (idx % 24) * 8;
      int grow = m0 + p * 128 + r;
      int colg = n0 + c8;
      int sel = colg >> 10;
      *(short8*)&outb[(size_t)sel * 4194304 + (size_t)grow * 1024 + (colg & 1023)] =
          *(const short8*)&Ep[r * 200 + c8];
    }
  }
}

// ---------------- final GEMM: 128x64 tile, 2 blocks/CU (sibling covers drains) ----------------
// out = attn_out * WoT^T + bo. grid 512 = 32tm x 16tn; XCD map 8tm x 8tn per XCD.
// 4 waves (2x2): wave tile 64x32, acc[4][2]. LDS 24KB: A[2][128*32], B[2][64*32].
__global__ __launch_bounds__(256, 2) void k_gemmO(
    const short* __restrict__ A, const short* __restrict__ BT,
    const float* __restrict__ bias0, float* __restrict__ outf) {
  __shared__ short Smem[12288];
  const int tid = threadIdx.x;
  const int lane = tid & 63, w = tid >> 6;
  const int g = lane >> 4, qi = lane & 15;
  const int wr = (w >> 1) * 64, wc = (w & 1) * 32;
  int bid = blockIdx.x;
  int xcd = bid & 7, ii = bid >> 3;            // 64 tiles per XCD: 8tm x 8tn
  const int tm = (xcd >> 1) * 8 + (ii >> 3);
  const int tn = (xcd & 1) * 8 + (ii & 7);
  const int m0 = tm * 128, n0 = tn * 64;
  const size_t K = 1024;
  const short* Ab = A + (size_t)m0 * K;
  const short* Bb = BT + (size_t)n0 * K;

  auto stage = [&](int buf, int k0) {
    short* Asb = Smem + buf * 4096;
    short* Bsb = Smem + 8192 + buf * 2048;
#pragma unroll
    for (int i = 0; i < 2; ++i) {
      int cidx = tid + i * 256;
      int r = cidx >> 2;
      int csw = ((cidx & 3) ^ ((r >> 1) & 3)) << 3;
      __builtin_amdgcn_global_load_lds((GU*)(Ab + (size_t)r * K + k0 + csw),
                                       (LU*)(&Asb[cidx * 8]), 16, 0, 0);
    }
    {
      int r = tid >> 2;
      int csw = ((tid & 3) ^ ((r >> 1) & 3)) << 3;
      __builtin_amdgcn_global_load_lds((GU*)(Bb + (size_t)r * K + k0 + csw),
                                       (LU*)(&Bsb[tid * 8]), 16, 0, 0);
    }
  };

  f32x4 acc[4][2];
#pragma unroll
  for (int i = 0; i < 4; ++i)
#pragma unroll
    for (int j = 0; j < 2; ++j) acc[i][j] = (f32x4)(0.0f);

  stage(0, 0);
  __syncthreads();
  for (int kt = 0; kt < 32; ++kt) {
    int cur = kt & 1;
    if (kt < 31) stage(cur ^ 1, (kt + 1) * 32);
    const short* Asb = Smem + cur * 4096;
    const short* Bsb = Smem + 8192 + cur * 2048;
    bf16x8 a[4], b[2];
#pragma unroll
    for (int mf = 0; mf < 4; ++mf) {
      int R = wr + mf * 16 + qi;
      a[mf] = *(const bf16x8*)&Asb[R * 32 + ((g ^ ((R >> 1) & 3)) << 3)];
    }
#pragma unroll
    for (int nf = 0; nf < 2; ++nf) {
      int R = wc + nf * 16 + qi;
      b[nf] = *(const bf16x8*)&Bsb[R * 32 + ((g ^ ((R >> 1) & 3)) << 3)];
    }
#pragma unroll
    for (int mf = 0; mf < 4; ++mf)
#pragma unroll
      for (int nf = 0; nf < 2; ++nf)
        acc[mf][nf] = __builtin_amdgcn_mfma_f32_16x16x32_bf16(a[mf], b[nf], acc[mf][nf], 0, 0, 0);
    __syncthreads();
  }

  float* Ft = (float*)Smem;                  // [32][72]
  float bv[2];
#pragma unroll
  for (int nf = 0; nf < 2; ++nf) bv[nf] = bias0[n0 + wc + nf * 16 + qi];
#pragma unroll
  for (int mf = 0; mf < 4; ++mf) {
    __syncthreads();
#pragma unroll
    for (int nf = 0; nf < 2; ++nf)
#pragma unroll
      for (int j = 0; j < 4; ++j)
        Ft[((w >> 1) * 16 + g * 4 + j) * 72 + wc + nf * 16 + qi] = acc[mf][nf][j] + bv[nf];
    __syncthreads();
#pragma unroll
    for (int i = 0; i < 2; ++i) {
      int idx = tid + i * 256;
      int r = idx >> 4, c4 = (idx & 15) << 2;
      int row = m0 + ((r >> 4) << 6) + mf * 16 + (r & 15);
      *(f32x4*)&outf[(size_t)row * 1024 + n0 + c4] = *(const f32x4*)&Ft[r * 72 + c4];
    }
  }
}

// ---------------- banded flash attention: QBLK=128, 8 waves, 2 blocks/CU ----------------
// grid 512 = b(2) x h(16) x qt(16 tiles of 128 q-rows). Band per tile: 6 chunks of 64
// (cc 0..5, kb0 = q0-128+cc*64, clamped); cc in {2,3} fully inside band (mask-free).
// Halves K/V re-reads and per-work barrier count vs QBLK=64. V staged with rotated-column
// transpose: Vs[d*72 + ((s + 8*(d>>3)) & 63)] = v[s][d]; PV b128 reads slot-uniform.
__global__ __launch_bounds__(512, 4) void k_attn(const short* __restrict__ qg_,
                                                 const short* __restrict__ kg_,
                                                 const short* __restrict__ vg_,
                                                 short* __restrict__ outp) {
  __shared__ short Qs[128 * 72];
  __shared__ short Ks[64 * 72];
  __shared__ short Vs[64 * 72];
  __shared__ short Ps[8][16 * 72];
  int bid = blockIdx.x;
  int qt = bid & 15, h = (bid >> 4) & 15, b = bid >> 8;
  int q0 = qt * 128;
  int tid = threadIdx.x, lane = tid & 63, w = tid >> 6;
  int g = lane >> 4, qi = lane & 15;

  const short* qsrc = qg_ + ((size_t)b * 2048 + q0) * 1024 + h * 64;
#pragma unroll
  for (int i = 0; i < 2; ++i) {
    int idx = tid + i * 512;
    int r = idx >> 3, c = (idx & 7) << 3;
    *(short8*)&Qs[r * 72 + c] = *(const short8*)&qsrc[(size_t)r * 1024 + c];
  }
  __syncthreads();
  bf16x8 qf0 = *(const bf16x8*)&Qs[(w * 16 + qi) * 72 + g * 8];
  bf16x8 qf1 = *(const bf16x8*)&Qs[(w * 16 + qi) * 72 + 32 + g * 8];

  float m = -1e30f, l = 0.f;
  f32x4 oacc[4];
#pragma unroll
  for (int i = 0; i < 4; ++i) oacc[i] = (f32x4)(0.0f);
  int qglob = q0 + w * 16 + qi;

  for (int cc = 0; cc < 6; ++cc) {
    int kb0 = q0 - 128 + cc * 64;
    if (kb0 < 0 || kb0 >= 2048) continue;
    __syncthreads();
    const short* ksrc = kg_ + ((size_t)b * 2048 + kb0) * 1024 + h * 64;
    const short* vsrc = vg_ + ((size_t)b * 2048 + kb0) * 1024 + h * 64;
    {
      int r = tid >> 3, c = (tid & 7) << 3;
      *(short8*)&Ks[r * 72 + c] = *(const short8*)&ksrc[(size_t)r * 1024 + c];
      short8 vv = *(const short8*)&vsrc[(size_t)r * 1024 + c];
#pragma unroll
      for (int j = 0; j < 8; ++j) {
        int d = c + j;
        Vs[d * 72 + ((r + ((d >> 3) << 3)) & 63)] = vv[j];
      }
    }
    __syncthreads();

    f32x4 st[4];
#pragma unroll
    for (int i = 0; i < 4; ++i) st[i] = (f32x4)(0.0f);
#pragma unroll
    for (int mf = 0; mf < 4; ++mf) {
      bf16x8 kf0 = *(const bf16x8*)&Ks[(mf * 16 + qi) * 72 + g * 8];
      bf16x8 kf1 = *(const bf16x8*)&Ks[(mf * 16 + qi) * 72 + 32 + g * 8];
      st[mf] = __builtin_amdgcn_mfma_f32_16x16x32_bf16(kf0, qf0, st[mf], 0, 0, 0);
      st[mf] = __builtin_amdgcn_mfma_f32_16x16x32_bf16(kf1, qf1, st[mf], 0, 0, 0);
    }

    float pv[16];
    float pm = -1e30f;
    if (cc == 2 || cc == 3) {           // fully inside band for all 128 q-rows
#pragma unroll
      for (int mf = 0; mf < 4; ++mf)
#pragma unroll
        for (int j = 0; j < 4; ++j) {
          float s = st[mf][j] * 0.125f;
          pv[mf * 4 + j] = s;
          pm = fmaxf(pm, s);
        }
    } else {
#pragma unroll
      for (int mf = 0; mf < 4; ++mf)
#pragma unroll
        for (int j = 0; j < 4; ++j) {
          int kcol = kb0 + mf * 16 + g * 4 + j;
          float s = st[mf][j] * 0.125f;
          int d = kcol - qglob;
          bool valid = (d >= -128) && (d <= 128);
          s = valid ? s : -1e30f;
          pv[mf * 4 + j] = s;
          pm = fmaxf(pm, s);
        }
    }
    pm = fmaxf(pm, __shfl_xor(pm, 16));
    pm = fmaxf(pm, __shfl_xor(pm, 32));
    float mnew = fmaxf(m, pm);
    float scale = __expf(m - mnew);
    float ls = 0.f;
#pragma unroll
    for (int e = 0; e < 16; ++e) {
      float p = pv[e] > -1e29f ? __expf(pv[e] - mnew) : 0.f;
      pv[e] = p;
      ls += p;
    }
    ls += __shfl_xor(ls, 16);
    ls += __shfl_xor(ls, 32);
    l = l * scale + ls;
    m = mnew;
#pragma unroll
    for (int mf = 0; mf < 4; ++mf) oacc[mf] *= scale;

#pragma unroll
    for (int f = 0; f < 4; ++f) {
      short4v pk;
#pragma unroll
      for (int j = 0; j < 4; ++j) pk[j] = f2bf(pv[f * 4 + j]);
      *(short4v*)&Ps[w][qi * 72 + f * 16 + g * 4] = pk;
    }

#pragma unroll
    for (int ks = 0; ks < 2; ++ks) {
      bf16x8 pf = *(const bf16x8*)&Ps[w][qi * 72 + ks * 32 + g * 8];
#pragma unroll
      for (int mf = 0; mf < 4; ++mf) {
        int dd = mf * 16 + qi;
        int pc = ((ks * 32 + g * 8) + ((dd >> 3) << 3)) & 63;
        bf16x8 vf = *(const bf16x8*)&Vs[dd * 72 + pc];
        oacc[mf] = __builtin_amdgcn_mfma_f32_16x16x32_bf16(vf, pf, oacc[mf], 0, 0, 0);
      }
    }
  }

  // epilogue: /l, per-wave rows into Os (=Qs, 128x72), coalesced bf16 store
  short* Os = Qs;
  float inv = 1.f / l;
#pragma unroll
  for (int mf = 0; mf < 4; ++mf) {
    short4v pk;
#pragma unroll
    for (int j = 0; j < 4; ++j) pk[j] = f2bf(oacc[mf][j] * inv);
    *(short4v*)&Os[(w * 16 + qi) * 72 + mf * 16 + g * 4] = pk;
  }
  __syncthreads();
  short* dst = outp + ((size_t)b * 2048 + q0) * 1024 + h * 64;
  int r = tid >> 2, c16 = (tid & 3) << 4;
  *(short8*)&dst[(size_t)r * 1024 + c16] = *(const short8*)&Os[r * 72 + c16];
  *(short8*)&dst[(size_t)r * 1024 + c16 + 8] = *(const short8*)&Os[r * 72 + c16 + 8];
}

extern "C" void kernel_launch(void* const* d_in, const int* in_sizes, int n_in,
                              void* d_out, int out_size, void* d_ws, size_t ws_size,
                              hipStream_t stream) {
  const float* x  = (const float*)d_in[0];
  const float* Wq = (const float*)d_in[1];
  const float* bq = (const float*)d_in[2];
  const float* Wk = (const float*)d_in[3];
  const float* bk = (const float*)d_in[4];
  const float* Wv = (const float*)d_in[5];
  const float* bv = (const float*)d_in[6];
  const float* Wo = (const float*)d_in[7];
  const float* bo = (const float*)d_in[8];

  short* ws = (short*)d_ws;
  // layout (shorts): [0,4M) xb (dead after QKV GEMM) -> attn_out ; [4M,16M) q,k,v ;
  // [16M,20M) WqT,WkT,WvT,WoT.  v stays live through k_attn (read directly).
  short* xb       = ws;
  short* qkv      = ws + 4194304;
  short* vbuf     = qkv + 2 * 4194304;
  short* attn_out = ws;            // aliases xb (dead after QKV GEMM)
  short* WT       = ws + 4 * 4194304;

  k_prep<<<3072, 256, 0, stream>>>(x, Wq, Wk, Wv, Wo, xb, WT);
  k_gemm256<<<256, 512, 0, stream>>>(xb, WT, bq, bk, bv, qkv);
  k_attn<<<512, 512, 0, stream>>>(qkv, qkv + 4194304, vbuf, attn_out);
  k_gemmO<<<512, 256, 0, stream>>>(attn_out, WT + 3 * 1048576, bo, (float*)d_out);
}

// Round 17
// 81.848 us; speedup vs baseline: 1.0198x; 1.0026x over previous
//
#include <hip/hip_runtime.h>
#include <cstdint>
#include <cstddef>

typedef __attribute__((ext_vector_type(8))) short short8;
typedef __attribute__((ext_vector_type(4))) short short4v;
typedef __attribute__((ext_vector_type(4))) float f32x4;
typedef short8 bf16x8;

typedef __attribute__((address_space(1))) const unsigned GU;
typedef __attribute__((address_space(3))) unsigned LU;

__device__ __forceinline__ short f2bf(float f) {
  unsigned u = __builtin_bit_cast(unsigned, f);
  u += 0x7fffu + ((u >> 16) & 1u);   // RNE; inputs are finite normals
  return (short)(u >> 16);
}

// ---------------- fused: cast x (f32->bf16) + weight transpose ----------------
__global__ __launch_bounds__(256) void k_prep(const float* __restrict__ x,
                                              const float* __restrict__ W0, const float* __restrict__ W1,
                                              const float* __restrict__ W2, const float* __restrict__ W3,
                                              short* __restrict__ xb, short* __restrict__ WT) {
  __shared__ short T[64 * 72];
  int bid = blockIdx.x;
  int tid = threadIdx.x;
  if (bid < 2048) {
    size_t i = ((size_t)bid * 256 + tid) * 8;
    f32x4 a = *(const f32x4*)(x + i);
    f32x4 b = *(const f32x4*)(x + i + 4);
    short8 o;
#pragma unroll
    for (int j = 0; j < 4; ++j) { o[j] = f2bf(a[j]); o[4 + j] = f2bf(b[j]); }
    *(short8*)(xb + i) = o;
    return;
  }
  bid -= 2048;
  int widx = bid >> 8;
  int t = bid & 255;
  int kr = (t >> 4) * 64, nc = (t & 15) * 64;
  const float* W = widx == 0 ? W0 : widx == 1 ? W1 : widx == 2 ? W2 : W3;
  short* out = WT + (size_t)widx * 1048576;
#pragma unroll
  for (int i = 0; i < 4; ++i) {
    int idx = tid + i * 256;          // 1024 quads of 4 floats
    int k = idx >> 4, n4 = (idx & 15) << 2;
    f32x4 v = *(const f32x4*)(W + (size_t)(kr + k) * 1024 + nc + n4);
#pragma unroll
    for (int j = 0; j < 4; ++j) T[(n4 + j) * 72 + k] = f2bf(v[j]);
  }
  __syncthreads();
#pragma unroll
  for (int i = 0; i < 2; ++i) {
    int idx = tid + i * 256;
    int n = idx >> 3, k8 = (idx & 7) << 3;
    *(short8*)(out + (size_t)(nc + n) * 1024 + kr + k8) = *(const short8*)&T[n * 72 + k8];
  }
}

// ================= 256M x 192N QKV GEMM — counted vmcnt + compiler-free scheduling ==========
// Same region rotation / stage placement / vmcnt(3) as round 13, but NO sched_barrier,
// NO asm lgkmcnt, NO setprio (m141: order-pinning defeats compiler scheduling; m190:
// setprio negative on lockstep GEMM). Raw s_barrier pairs carry cross-wave LDS safety:
// every staged region's prior readers are >=2 barriers upstream (1-barrier motion safe);
// intra-wave ds_read->MFMA waits are compiler-inserted (G7).
__global__ __launch_bounds__(512, 1) void k_gemm256(
    const short* __restrict__ A, const short* __restrict__ BT,
    const float* __restrict__ bias0, const float* __restrict__ bias1, const float* __restrict__ bias2,
    short* __restrict__ outb) {
  __shared__ short S[57344];
  const int tid = threadIdx.x;
  const int lane = tid & 63, w = tid >> 6;
  const int g = lane >> 4, qi = lane & 15;
  const int wm = w >> 2, wn = w & 3;
  int bid = blockIdx.x;
  int xcd = bid & 7, ii = bid >> 3;           // 32 tiles per XCD, 4x8 rectangle
  const int tm = (xcd >> 1) * 4 + (ii >> 3);
  const int tn = (xcd & 1) * 8 + (ii & 7);
  const int m0 = tm * 256, n0 = tn * 192;
  const size_t K = 1024;
  const short* Ab = A + (size_t)m0 * K;
  const short* Bb = BT + (size_t)n0 * K;

  auto stage64 = [&](int roff, const short* gbase, int kt) {
    int r = tid >> 3;
    int js = ((tid & 7) ^ (r & 7)) << 3;      // pre-swizzled global chunk
    __builtin_amdgcn_global_load_lds((GU*)(gbase + (size_t)r * K + kt * 64 + js),
                                     (LU*)(&S[roff + tid * 8]), 16, 0, 0);
  };
  auto lda_a = [&](int bbase, int mf, int kk) -> bf16x8 {
    int row = (mf & 3) * 16 + qi;
    int reg = wm * 2 + (mf >> 2);
    return *(const bf16x8*)&S[bbase + reg * 4096 + row * 64 + (((kk * 4 + g) ^ (row & 7)) << 3)];
  };
  auto lda_b = [&](int bbase, int nf, int kk) -> bf16x8 {
    int c = wn * 48 + nf * 16 + qi;
    int reg = c >> 6, row = c & 63;
    return *(const bf16x8*)&S[bbase + 16384 + reg * 4096 + row * 64 + (((kk * 4 + g) ^ (row & 7)) << 3)];
  };

  f32x4 acc[8][3];
#pragma unroll
  for (int i = 0; i < 8; ++i)
#pragma unroll
    for (int j = 0; j < 3; ++j) acc[i][j] = (f32x4)(0.0f);

#define MFA(mi, ni, av, bv) \
  acc[mi][ni] = __builtin_amdgcn_mfma_f32_16x16x32_bf16(av, bv, acc[mi][ni], 0, 0, 0)
#define MF12(Aa, Bb_, o) \
  MFA((o)+0,0,(Aa)[(o)+0],(Bb_)[0]); MFA((o)+0,1,(Aa)[(o)+0],(Bb_)[1]); MFA((o)+0,2,(Aa)[(o)+0],(Bb_)[2]); \
  MFA((o)+1,0,(Aa)[(o)+1],(Bb_)[0]); MFA((o)+1,1,(Aa)[(o)+1],(Bb_)[1]); MFA((o)+1,2,(Aa)[(o)+1],(Bb_)[2]); \
  MFA((o)+2,0,(Aa)[(o)+2],(Bb_)[0]); MFA((o)+2,1,(Aa)[(o)+2],(Bb_)[1]); MFA((o)+2,2,(Aa)[(o)+2],(Bb_)[2]); \
  MFA((o)+3,0,(Aa)[(o)+3],(Bb_)[0]); MFA((o)+3,1,(Aa)[(o)+3],(Bb_)[1]); MFA((o)+3,2,(Aa)[(o)+3],(Bb_)[2])
#define PHASE_TAIL(MFMAS) do { \
    __builtin_amdgcn_s_barrier(); \
    MFMAS; \
    __builtin_amdgcn_s_barrier(); \
  } while (0)

  // prologue: T0 (A0-3,B0-2) into buf0 + T1.B0-2 into buf1
  stage64(0,     Ab,            0);
  stage64(4096,  Ab + 65536,    0);
  stage64(8192,  Ab + 131072,   0);
  stage64(12288, Ab + 196608,   0);
  stage64(16384, Bb,            0);
  stage64(20480, Bb + 65536,    0);
  stage64(24576, Bb + 131072,   0);
  stage64(28672 + 16384, Bb,          1);
  stage64(28672 + 20480, Bb + 65536,  1);
  stage64(28672 + 24576, Bb + 131072, 1);
  asm volatile("s_waitcnt vmcnt(3)" ::: "memory");   // T0 landed; T1.B in flight
  __builtin_amdgcn_s_barrier();

  for (int t = 0; t < 16; ++t) {
    const int b = t & 1, nb = b ^ 1;
    const int bb = b * 28672, nbb = nb * 28672;
    const int t1 = t + 1 < 15 ? t + 1 : 15;
    const int t2 = t + 2 < 15 ? t + 2 : 15;
    bf16x8 aA[8], aB[3], cA[8], cB[3];

    // ---- P0 ----
#pragma unroll
    for (int mf = 0; mf < 4; ++mf) aA[mf] = lda_a(bb, mf, 0);
#pragma unroll
    for (int nf = 0; nf < 3; ++nf) aB[nf] = lda_b(bb, nf, 0);
    stage64(nbb,        Ab,         t1);             // (T+1).A0
    stage64(nbb + 4096, Ab + 65536, t1);             // (T+1).A1
    PHASE_TAIL(MF12(aA, aB, 0));
    // ---- P1 ----
#pragma unroll
    for (int mf = 4; mf < 8; ++mf) aA[mf] = lda_a(bb, mf, 0);
#pragma unroll
    for (int nf = 0; nf < 3; ++nf) cB[nf] = lda_b(bb, nf, 1);
    stage64(nbb + 8192,  Ab + 131072, t1);           // (T+1).A2
    stage64(nbb + 12288, Ab + 196608, t1);           // (T+1).A3
    PHASE_TAIL(MF12(aA, aB, 4));
    // ---- P2 ----
#pragma unroll
    for (int mf = 0; mf < 4; ++mf) cA[mf] = lda_a(bb, mf, 1);
    stage64(bb + 16384, Bb,         t2);             // (T+2).B0
    stage64(bb + 20480, Bb + 65536, t2);             // (T+2).B1
    PHASE_TAIL(MF12(cA, cB, 0));
    // ---- P3 ----
#pragma unroll
    for (int mf = 4; mf < 8; ++mf) cA[mf] = lda_a(bb, mf, 1);
    stage64(bb + 24576, Bb + 131072, t2);            // (T+2).B2
    asm volatile("s_waitcnt vmcnt(3)" ::: "memory"); // (T+1) fully landed
    PHASE_TAIL(MF12(cA, cB, 4));
  }
#undef PHASE_TAIL
#undef MF12
#undef MFA

  // epilogue: drain clamped stages, then LDS-transpose coalesced bf16 stores
  asm volatile("s_waitcnt vmcnt(0)" ::: "memory");
  __syncthreads();
  float bv[3];
#pragma unroll
  for (int nf = 0; nf < 3; ++nf) {
    int colg = n0 + wn * 48 + nf * 16 + qi;
    int sel = colg >> 10;
    const float* bias = sel == 0 ? bias0 : (sel == 1 ? bias1 : bias2);
    bv[nf] = bias[colg & 1023];
  }
  short* Ep = S;                                       // [128][200]
#pragma unroll
  for (int p = 0; p < 2; ++p) {
    __syncthreads();
    if (wm == p) {
#pragma unroll
      for (int mf = 0; mf < 8; ++mf)
#pragma unroll
        for (int nf = 0; nf < 3; ++nf)
#pragma unroll
          for (int j = 0; j < 4; ++j)
            Ep[(mf * 16 + g * 4 + j) * 200 + wn * 48 + nf * 16 + qi] =
                f2bf(acc[mf][nf][j] + bv[nf]);
    }
    __syncthreads();
#pragma unroll
    for (int i = 0; i < 6; ++i) {
      int idx = tid + i * 512;                         // 3072 chunks of 8 bf16
      int r = idx / 24, c8 = (idx % 24) * 8;
      int grow = m0 + p * 128 + r;
      int colg = n0 + c8;
      int sel = colg >> 10;
      *(short8*)&outb[(size_t)sel * 4194304 + (size_t)grow * 1024 + (colg & 1023)] =
          *(const short8*)&Ep[r * 200 + c8];
    }
  }
}

// ---------------- final GEMM: 128x64 tile, 2 blocks/CU ----------------
__global__ __launch_bounds__(256, 2) void k_gemmO(
    const short* __restrict__ A, const short* __restrict__ BT,
    const float* __restrict__ bias0, float* __restrict__ outf) {
  __shared__ short Smem[12288];
  const int tid = threadIdx.x;
  const int lane = tid & 63, w = tid >> 6;
  const int g = lane >> 4, qi = lane & 15;
  const int wr = (w >> 1) * 64, wc = (w & 1) * 32;
  int bid = blockIdx.x;
  int xcd = bid & 7, ii = bid >> 3;            // 64 tiles per XCD: 8tm x 8tn
  const int tm = (xcd >> 1) * 8 + (ii >> 3);
  const int tn = (xcd & 1) * 8 + (ii & 7);
  const int m0 = tm * 128, n0 = tn * 64;
  const size_t K = 1024;
  const short* Ab = A + (size_t)m0 * K;
  const short* Bb = BT + (size_t)n0 * K;

  auto stage = [&](int buf, int k0) {
    short* Asb = Smem + buf * 4096;
    short* Bsb = Smem + 8192 + buf * 2048;
#pragma unroll
    for (int i = 0; i < 2; ++i) {
      int cidx = tid + i * 256;
      int r = cidx >> 2;
      int csw = ((cidx & 3) ^ ((r >> 1) & 3)) << 3;
      __builtin_amdgcn_global_load_lds((GU*)(Ab + (size_t)r * K + k0 + csw),
                                       (LU*)(&Asb[cidx * 8]), 16, 0, 0);
    }
    {
      int r = tid >> 2;
      int csw = ((tid & 3) ^ ((r >> 1) & 3)) << 3;
      __builtin_amdgcn_global_load_lds((GU*)(Bb + (size_t)r * K + k0 + csw),
                                       (LU*)(&Bsb[tid * 8]), 16, 0, 0);
    }
  };

  f32x4 acc[4][2];
#pragma unroll
  for (int i = 0; i < 4; ++i)
#pragma unroll
    for (int j = 0; j < 2; ++j) acc[i][j] = (f32x4)(0.0f);

  stage(0, 0);
  __syncthreads();
  for (int kt = 0; kt < 32; ++kt) {
    int cur = kt & 1;
    if (kt < 31) stage(cur ^ 1, (kt + 1) * 32);
    const short* Asb = Smem + cur * 4096;
    const short* Bsb = Smem + 8192 + cur * 2048;
    bf16x8 a[4], b[2];
#pragma unroll
    for (int mf = 0; mf < 4; ++mf) {
      int R = wr + mf * 16 + qi;
      a[mf] = *(const bf16x8*)&Asb[R * 32 + ((g ^ ((R >> 1) & 3)) << 3)];
    }
#pragma unroll
    for (int nf = 0; nf < 2; ++nf) {
      int R = wc + nf * 16 + qi;
      b[nf] = *(const bf16x8*)&Bsb[R * 32 + ((g ^ ((R >> 1) & 3)) << 3)];
    }
#pragma unroll
    for (int mf = 0; mf < 4; ++mf)
#pragma unroll
      for (int nf = 0; nf < 2; ++nf)
        acc[mf][nf] = __builtin_amdgcn_mfma_f32_16x16x32_bf16(a[mf], b[nf], acc[mf][nf], 0, 0, 0);
    __syncthreads();
  }

  float* Ft = (float*)Smem;                  // [32][72]
  float bv[2];
#pragma unroll
  for (int nf = 0; nf < 2; ++nf) bv[nf] = bias0[n0 + wc + nf * 16 + qi];
#pragma unroll
  for (int mf = 0; mf < 4; ++mf) {
    __syncthreads();
#pragma unroll
    for (int nf = 0; nf < 2; ++nf)
#pragma unroll
      for (int j = 0; j < 4; ++j)
        Ft[((w >> 1) * 16 + g * 4 + j) * 72 + wc + nf * 16 + qi] = acc[mf][nf][j] + bv[nf];
    __syncthreads();
#pragma unroll
    for (int i = 0; i < 2; ++i) {
      int idx = tid + i * 256;
      int r = idx >> 4, c4 = (idx & 15) << 2;
      int row = m0 + ((r >> 4) << 6) + mf * 16 + (r & 15);
      *(f32x4*)&outf[(size_t)row * 1024 + n0 + c4] = *(const f32x4*)&Ft[r * 72 + c4];
    }
  }
}

// ---------------- banded flash attention: QBLK=128, 8 waves, 2 blocks/CU ----------------
__global__ __launch_bounds__(512, 4) void k_attn(const short* __restrict__ qg_,
                                                 const short* __restrict__ kg_,
                                                 const short* __restrict__ vg_,
                                                 short* __restrict__ outp) {
  __shared__ short Qs[128 * 72];
  __shared__ short Ks[64 * 72];
  __shared__ short Vs[64 * 72];
  __shared__ short Ps[8][16 * 72];
  int bid = blockIdx.x;
  int qt = bid & 15, h = (bid >> 4) & 15, b = bid >> 8;
  int q0 = qt * 128;
  int tid = threadIdx.x, lane = tid & 63, w = tid >> 6;
  int g = lane >> 4, qi = lane & 15;

  const short* qsrc = qg_ + ((size_t)b * 2048 + q0) * 1024 + h * 64;
#pragma unroll
  for (int i = 0; i < 2; ++i) {
    int idx = tid + i * 512;
    int r = idx >> 3, c = (idx & 7) << 3;
    *(short8*)&Qs[r * 72 + c] = *(const short8*)&qsrc[(size_t)r * 1024 + c];
  }
  __syncthreads();
  bf16x8 qf0 = *(const bf16x8*)&Qs[(w * 16 + qi) * 72 + g * 8];
  bf16x8 qf1 = *(const bf16x8*)&Qs[(w * 16 + qi) * 72 + 32 + g * 8];

  float m = -1e30f, l = 0.f;
  f32x4 oacc[4];
#pragma unroll
  for (int i = 0; i < 4; ++i) oacc[i] = (f32x4)(0.0f);
  int qglob = q0 + w * 16 + qi;

  for (int cc = 0; cc < 6; ++cc) {
    int kb0 = q0 - 128 + cc * 64;
    if (kb0 < 0 || kb0 >= 2048) continue;
    __syncthreads();
    const short* ksrc = kg_ + ((size_t)b * 2048 + kb0) * 1024 + h * 64;
    const short* vsrc = vg_ + ((size_t)b * 2048 + kb0) * 1024 + h * 64;
    {
      int r = tid >> 3, c = (tid & 7) << 3;
      *(short8*)&Ks[r * 72 + c] = *(const short8*)&ksrc[(size_t)r * 1024 + c];
      short8 vv = *(const short8*)&vsrc[(size_t)r * 1024 + c];
#pragma unroll
      for (int j = 0; j < 8; ++j) {
        int d = c + j;
        Vs[d * 72 + ((r + ((d >> 3) << 3)) & 63)] = vv[j];
      }
    }
    __syncthreads();

    f32x4 st[4];
#pragma unroll
    for (int i = 0; i < 4; ++i) st[i] = (f32x4)(0.0f);
#pragma unroll
    for (int mf = 0; mf < 4; ++mf) {
      bf16x8 kf0 = *(const bf16x8*)&Ks[(mf * 16 + qi) * 72 + g * 8];
      bf16x8 kf1 = *(const bf16x8*)&Ks[(mf * 16 + qi) * 72 + 32 + g * 8];
      st[mf] = __builtin_amdgcn_mfma_f32_16x16x32_bf16(kf0, qf0, st[mf], 0, 0, 0);
      st[mf] = __builtin_amdgcn_mfma_f32_16x16x32_bf16(kf1, qf1, st[mf], 0, 0, 0);
    }

    float pv[16];
    float pm = -1e30f;
    if (cc == 2 || cc == 3) {           // fully inside band for all 128 q-rows
#pragma unroll
      for (int mf = 0; mf < 4; ++mf)
#pragma unroll
        for (int j = 0; j < 4; ++j) {
          float s = st[mf][j] * 0.125f;
          pv[mf * 4 + j] = s;
          pm = fmaxf(pm, s);
        }
    } else {
#pragma unroll
      for (int mf = 0; mf < 4; ++mf)
#pragma unroll
        for (int j = 0; j < 4; ++j) {
          int kcol = kb0 + mf * 16 + g * 4 + j;
          float s = st[mf][j] * 0.125f;
          int d = kcol - qglob;
          bool valid = (d >= -128) && (d <= 128);
          s = valid ? s : -1e30f;
          pv[mf * 4 + j] = s;
          pm = fmaxf(pm, s);
        }
    }
    pm = fmaxf(pm, __shfl_xor(pm, 16));
    pm = fmaxf(pm, __shfl_xor(pm, 32));
    float mnew = fmaxf(m, pm);
    float scale = __expf(m - mnew);
    float ls = 0.f;
#pragma unroll
    for (int e = 0; e < 16; ++e) {
      float p = pv[e] > -1e29f ? __expf(pv[e] - mnew) : 0.f;
      pv[e] = p;
      ls += p;
    }
    ls += __shfl_xor(ls, 16);
    ls += __shfl_xor(ls, 32);
    l = l * scale + ls;
    m = mnew;
#pragma unroll
    for (int mf = 0; mf < 4; ++mf) oacc[mf] *= scale;

#pragma unroll
    for (int f = 0; f < 4; ++f) {
      short4v pk;
#pragma unroll
      for (int j = 0; j < 4; ++j) pk[j] = f2bf(pv[f * 4 + j]);
      *(short4v*)&Ps[w][qi * 72 + f * 16 + g * 4] = pk;
    }

#pragma unroll
    for (int ks = 0; ks < 2; ++ks) {
      bf16x8 pf = *(const bf16x8*)&Ps[w][qi * 72 + ks * 32 + g * 8];
#pragma unroll
      for (int mf = 0; mf < 4; ++mf) {
        int dd = mf * 16 + qi;
        int pc = ((ks * 32 + g * 8) + ((dd >> 3) << 3)) & 63;
        bf16x8 vf = *(const bf16x8*)&Vs[dd * 72 + pc];
        oacc[mf] = __builtin_amdgcn_mfma_f32_16x16x32_bf16(vf, pf, oacc[mf], 0, 0, 0);
      }
    }
  }

  // epilogue: /l, per-wave rows into Os (=Qs, 128x72), coalesced bf16 store
  short* Os = Qs;
  float inv = 1.f / l;
#pragma unroll
  for (int mf = 0; mf < 4; ++mf) {
    short4v pk;
#pragma unroll
    for (int j = 0; j < 4; ++j) pk[j] = f2bf(oacc[mf][j] * inv);
    *(short4v*)&Os[(w * 16 + qi) * 72 + mf * 16 + g * 4] = pk;
  }
  __syncthreads();
  short* dst = outp + ((size_t)b * 2048 + q0) * 1024 + h * 64;
  int r = tid >> 2, c16 = (tid & 3) << 4;
  *(short8*)&dst[(size_t)r * 1024 + c16] = *(const short8*)&Os[r * 72 + c16];
  *(short8*)&dst[(size_t)r * 1024 + c16 + 8] = *(const short8*)&Os[r * 72 + c16 + 8];
}

extern "C" void kernel_launch(void* const* d_in, const int* in_sizes, int n_in,
                              void* d_out, int out_size, void* d_ws, size_t ws_size,
                              hipStream_t stream) {
  const float* x  = (const float*)d_in[0];
  const float* Wq = (const float*)d_in[1];
  const float* bq = (const float*)d_in[2];
  const float* Wk = (const float*)d_in[3];
  const float* bk = (const float*)d_in[4];
  const float* Wv = (const float*)d_in[5];
  const float* bv = (const float*)d_in[6];
  const float* Wo = (const float*)d_in[7];
  const float* bo = (const float*)d_in[8];

  short* ws = (short*)d_ws;
  // layout (shorts): [0,4M) xb (dead after QKV GEMM) -> attn_out ; [4M,16M) q,k,v ;
  // [16M,20M) WqT,WkT,WvT,WoT.  v stays live through k_attn (read directly).
  short* xb       = ws;
  short* qkv      = ws + 4194304;
  short* vbuf     = qkv + 2 * 4194304;
  short* attn_out = ws;            // aliases xb (dead after QKV GEMM)
  short* WT       = ws + 4 * 4194304;

  k_prep<<<3072, 256, 0, stream>>>(x, Wq, Wk, Wv, Wo, xb, WT);
  k_gemm256<<<256, 512, 0, stream>>>(xb, WT, bq, bk, bv, qkv);
  k_attn<<<512, 512, 0, stream>>>(qkv, qkv + 4194304, vbuf, attn_out);
  k_gemmO<<<512, 256, 0, stream>>>(attn_out, WT + 3 * 1048576, bo, (float*)d_out);
}